// Round 1
// baseline (3699.176 us; speedup 1.0000x reference)
//
#include <hip/hip_runtime.h>

// SALSA attention, B=4, C=64, IC=16, H=W=256, k=7, s=4 -> L=64x64=4096 patches,
// patch dim KD=16*49=784. Round 0: correctness-first all-fp32 pipeline.
//
// ws layout (floats), reused across the 4 sequential batches (~135 MB):
//   G,P,T images (16,256,256) x3 | Q,K,V (4096,784) x3 | ATT (4096,4096) |
//   OUT (4096,784) | ZI (16,256,256)

#define CIN 64
#define ICN 16
#define HH 256
#define WID 256
#define HW (HH*WID)
#define LL 4096          // 64*64 patches
#define KD 784           // 16*49
#define NB 4

// ---------------- conv1x1 (64 -> 16) for G, P, T at once ----------------
__global__ __launch_bounds__(256) void conv1x1_3(
    const float* __restrict__ x,
    const float* __restrict__ Wg, const float* __restrict__ bg,
    const float* __restrict__ Wp, const float* __restrict__ bp,
    const float* __restrict__ Wt, const float* __restrict__ bt,
    float* __restrict__ G, float* __restrict__ P, float* __restrict__ T) {
  __shared__ float wg[ICN*CIN], wp[ICN*CIN], wt[ICN*CIN];
  int t = threadIdx.x;
  for (int i = t; i < ICN*CIN; i += 256) { wg[i]=Wg[i]; wp[i]=Wp[i]; wt[i]=Wt[i]; }
  __syncthreads();
  int p = blockIdx.x*256 + t;
  float aG[ICN], aP[ICN], aT[ICN];
#pragma unroll
  for (int o=0;o<ICN;o++){ aG[o]=bg[o]; aP[o]=bp[o]; aT[o]=bt[o]; }
  for (int c=0;c<CIN;c++){
    float xv = x[c*HW + p];
#pragma unroll
    for (int o=0;o<ICN;o++){
      aG[o] = fmaf(wg[o*CIN+c], xv, aG[o]);
      aP[o] = fmaf(wp[o*CIN+c], xv, aP[o]);
      aT[o] = fmaf(wt[o*CIN+c], xv, aT[o]);
    }
  }
#pragma unroll
  for (int o=0;o<ICN;o++){ G[o*HW+p]=aG[o]; P[o*HW+p]=aP[o]; T[o*HW+p]=aT[o]; }
}

// ---------------- unfold k=7 s=4, pad top/left=1 (SAME pads (1,2)) ----------------
__global__ __launch_bounds__(256) void unfold3(
    const float* __restrict__ G, const float* __restrict__ P, const float* __restrict__ T,
    float* __restrict__ Q, float* __restrict__ K, float* __restrict__ V){
  int idx = blockIdx.x*256 + threadIdx.x;
  if (idx >= LL*KD) return;
  int col = idx % KD, row = idx / KD;
  int c = col / 49; int r = col - c*49; int dy = r / 7; int dx = r - dy*7;
  int iy = row >> 6, ix = row & 63;
  int y = (iy<<2) + dy - 1, x = (ix<<2) + dx - 1;
  float g=0.f, pv=0.f, tv=0.f;
  if ((unsigned)y < HH && (unsigned)x < WID){
    int a = c*HW + y*WID + x;
    g = G[a]; pv = P[a]; tv = T[a];
  }
  Q[idx]=g; K[idx]=pv; V[idx]=tv;
}

// ---------------- ATT = 10 * Q(4096x784) @ K(4096x784)^T ----------------
__global__ __launch_bounds__(256) void gemm_qk(
    const float* __restrict__ Q, const float* __restrict__ K, float* __restrict__ ATT){
  __shared__ alignas(16) float Ast[16][68];
  __shared__ alignas(16) float Bst[16][68];
  int tid = threadIdx.x;
  int cx = tid & 15, cy = tid >> 4;
  int row0 = blockIdx.y * 64, col0 = blockIdx.x * 64;
  int lr = tid >> 2, lk = (tid & 3) << 2;
  float acc[4][4] = {};
  for (int k0 = 0; k0 < KD; k0 += 16){
    float4 av = *(const float4*)&Q[(size_t)(row0+lr)*KD + k0 + lk];
    float4 bv = *(const float4*)&K[(size_t)(col0+lr)*KD + k0 + lk];
    Ast[lk+0][lr]=av.x; Ast[lk+1][lr]=av.y; Ast[lk+2][lr]=av.z; Ast[lk+3][lr]=av.w;
    Bst[lk+0][lr]=bv.x; Bst[lk+1][lr]=bv.y; Bst[lk+2][lr]=bv.z; Bst[lk+3][lr]=bv.w;
    __syncthreads();
#pragma unroll
    for (int kk=0;kk<16;kk++){
      float4 a4 = *(const float4*)&Ast[kk][cy<<2];
      float4 b4 = *(const float4*)&Bst[kk][cx<<2];
      float ar[4] = {a4.x,a4.y,a4.z,a4.w};
      float br[4] = {b4.x,b4.y,b4.z,b4.w};
#pragma unroll
      for (int i=0;i<4;i++)
#pragma unroll
        for (int j=0;j<4;j++) acc[i][j] = fmaf(ar[i], br[j], acc[i][j]);
    }
    __syncthreads();
  }
#pragma unroll
  for (int i=0;i<4;i++){
    float4 o4 = make_float4(acc[i][0]*10.f, acc[i][1]*10.f, acc[i][2]*10.f, acc[i][3]*10.f);
    *(float4*)&ATT[(size_t)(row0+(cy<<2)+i)*LL + col0 + (cx<<2)] = o4;
  }
}

// ---------------- row softmax over 4096 ----------------
__global__ __launch_bounds__(256) void softmax_rows(float* __restrict__ ATT){
  __shared__ float red[256];
  int t = threadIdx.x;
  float* r = ATT + (size_t)blockIdx.x * LL;
  float v[16];
  float mx = -3.4e38f;
#pragma unroll
  for (int i=0;i<16;i++){ v[i] = r[t + (i<<8)]; mx = fmaxf(mx, v[i]); }
  red[t] = mx; __syncthreads();
  for (int s2=128;s2>0;s2>>=1){ if (t<s2) red[t]=fmaxf(red[t],red[t+s2]); __syncthreads(); }
  mx = red[0]; __syncthreads();
  float sum = 0.f;
#pragma unroll
  for (int i=0;i<16;i++){ v[i] = __expf(v[i]-mx); sum += v[i]; }
  red[t]=sum; __syncthreads();
  for (int s2=128;s2>0;s2>>=1){ if (t<s2) red[t]+=red[t+s2]; __syncthreads(); }
  float inv = 1.0f / red[0];
#pragma unroll
  for (int i=0;i<16;i++) r[t+(i<<8)] = v[i]*inv;
}

// ---------------- OUT = ATT(4096x4096) @ V(4096x784) ----------------
__global__ __launch_bounds__(256) void gemm_pv(
    const float* __restrict__ ATT, const float* __restrict__ V, float* __restrict__ OUT){
  __shared__ alignas(16) float Ast[16][68];
  __shared__ alignas(16) float Bs[16][68];
  int tid = threadIdx.x;
  int cx = tid & 15, cy = tid >> 4;
  int row0 = blockIdx.y * 64, col0 = blockIdx.x * 64;
  int lr = tid >> 2, lk = (tid & 3) << 2;   // A-tile: 64 rows x 16 k
  int kr = tid >> 4, cb = (tid & 15) << 2;  // B-tile: 16 k x 64 n
  float acc[4][4] = {};
  for (int k0 = 0; k0 < LL; k0 += 16){
    float4 av = *(const float4*)&ATT[(size_t)(row0+lr)*LL + k0 + lk];
    Ast[lk+0][lr]=av.x; Ast[lk+1][lr]=av.y; Ast[lk+2][lr]=av.z; Ast[lk+3][lr]=av.w;
    int bc = col0 + cb;
    float4 bv = make_float4(0.f,0.f,0.f,0.f);
    if (bc + 3 < KD) bv = *(const float4*)&V[(size_t)(k0+kr)*KD + bc];
    *(float4*)&Bs[kr][cb] = bv;
    __syncthreads();
#pragma unroll
    for (int kk=0;kk<16;kk++){
      float4 a4 = *(const float4*)&Ast[kk][cy<<2];
      float4 b4 = *(const float4*)&Bs[kk][cx<<2];
      float ar[4] = {a4.x,a4.y,a4.z,a4.w};
      float br[4] = {b4.x,b4.y,b4.z,b4.w};
#pragma unroll
      for (int i=0;i<4;i++)
#pragma unroll
        for (int j=0;j<4;j++) acc[i][j] = fmaf(ar[i], br[j], acc[i][j]);
    }
    __syncthreads();
  }
  int ccol = col0 + (cx<<2);
  if (ccol + 3 < KD){
#pragma unroll
    for (int i=0;i<4;i++){
      float4 o4 = make_float4(acc[i][0], acc[i][1], acc[i][2], acc[i][3]);
      *(float4*)&OUT[(size_t)(row0+(cy<<2)+i)*KD + ccol] = o4;
    }
  }
}

// ---------------- fold (pad=3) + divide by closed-form mask ----------------
__global__ __launch_bounds__(256) void fold_div(
    const float* __restrict__ OUT, float* __restrict__ ZI){
  int idx = blockIdx.x*256 + threadIdx.x;
  if (idx >= ICN*HW) return;
  int c = idx >> 16; int rem = idx & 65535; int y = rem >> 8; int x = rem & 255;
  int yc = y + 3, xc = x + 3;
  int i0 = (yc-3) >> 2; int i1 = yc >> 2; if (i1 > 63) i1 = 63;
  int j0 = (xc-3) >> 2; int j1 = xc >> 2; if (j1 > 63) j1 = 63;
  float s = 0.f;
  for (int i = i0; i <= i1; i++){
    int dy = yc - (i<<2);
    for (int j = j0; j <= j1; j++){
      int dx = xc - (j<<2);
      s += OUT[(size_t)((i<<6)+j)*KD + c*49 + dy*7 + dx];
    }
  }
  float mask = (float)((i1-i0+1)*(j1-j0+1));
  ZI[idx] = s / mask;
}

// ---------------- out = x + conv1x1(zi, Ww, bw) ----------------
__global__ __launch_bounds__(256) void final_out(
    const float* __restrict__ xin, const float* __restrict__ ZI,
    const float* __restrict__ Ww, const float* __restrict__ bw,
    float* __restrict__ out){
  int idx = blockIdx.x*256 + threadIdx.x;   // co*HW + p
  int co = idx >> 16;
  int p = idx & 65535;
  float acc = xin[idx] + bw[co];
#pragma unroll
  for (int ic=0; ic<ICN; ic++)
    acc = fmaf(Ww[co*ICN+ic], ZI[ic*HW + p], acc);
  out[idx] = acc;
}

extern "C" void kernel_launch(void* const* d_in, const int* in_sizes, int n_in,
                              void* d_out, int out_size, void* d_ws, size_t ws_size,
                              hipStream_t stream) {
  const float* xb = (const float*)d_in[0];
  const float* Wg = (const float*)d_in[1];
  const float* bg = (const float*)d_in[2];
  const float* Wt = (const float*)d_in[3];
  const float* bt = (const float*)d_in[4];
  const float* Wp = (const float*)d_in[5];
  const float* bp = (const float*)d_in[6];
  const float* Ww = (const float*)d_in[7];
  const float* bw = (const float*)d_in[8];
  float* out = (float*)d_out;

  float* w = (float*)d_ws;
  const size_t IMG = (size_t)ICN*HW;   // 1,048,576 floats
  const size_t QN  = (size_t)LL*KD;    // 3,211,264 floats
  float* G   = w;
  float* P   = G + IMG;
  float* T   = P + IMG;
  float* Qm  = T + IMG;
  float* Km  = Qm + QN;
  float* Vm  = Km + QN;
  float* ATT = Vm + QN;                 // 16,777,216 floats
  float* OUTm= ATT + (size_t)LL*LL;
  float* ZI  = OUTm + QN;               // total ~33.8M floats (~135 MB)

  for (int b = 0; b < NB; b++){
    const float* x = xb + (size_t)b*CIN*HW;
    conv1x1_3<<<HW/256, 256, 0, stream>>>(x, Wg,bg, Wp,bp, Wt,bt, G,P,T);
    unfold3<<<(int)((QN+255)/256), 256, 0, stream>>>(G,P,T, Qm,Km,Vm);
    gemm_qk<<<dim3(LL/64, LL/64), 256, 0, stream>>>(Qm, Km, ATT);
    softmax_rows<<<LL, 256, 0, stream>>>(ATT);
    gemm_pv<<<dim3((KD+63)/64, LL/64), 256, 0, stream>>>(ATT, Vm, OUTm);
    fold_div<<<(int)((IMG+255)/256), 256, 0, stream>>>(OUTm, ZI);
    final_out<<<CIN*HW/256, 256, 0, stream>>>(x, ZI, Ww, bw, out + (size_t)b*CIN*HW);
  }
}

// Round 3
// 1234.554 us; speedup vs baseline: 2.9964x; 2.9964x over previous
//
#include <hip/hip_runtime.h>

#define CIN 64
#define ICN 16
#define HH 256
#define WID 256
#define HW (HH*WID)
#define LL 4096          // 64*64 patches
#define KD 784           // 16*49
#define KDP 800          // padded to multiple of 32
#define NVT 896          // V^T rows (784 padded to 128 multiple)
#define NB 4

typedef __attribute__((ext_vector_type(8))) short short8;
typedef __attribute__((ext_vector_type(4))) float f32x4;

__device__ __forceinline__ unsigned short f2bf(float x){
  union { float f; unsigned u; } v; v.f = x;
  unsigned r = v.u + 0x7FFF + ((v.u >> 16) & 1);
  return (unsigned short)(r >> 16);
}
__device__ __forceinline__ float bf2f(unsigned short h){
  union { unsigned u; float f; } v; v.u = ((unsigned)h) << 16; return v.f;
}

// ---------------- conv1x1 (64 -> 16) for G, P, T at once ----------------
__global__ __launch_bounds__(256) void conv1x1_3(
    const float* __restrict__ x,
    const float* __restrict__ Wg, const float* __restrict__ bg,
    const float* __restrict__ Wp, const float* __restrict__ bp,
    const float* __restrict__ Wt, const float* __restrict__ bt,
    float* __restrict__ G, float* __restrict__ P, float* __restrict__ T) {
  __shared__ float wg[ICN*CIN], wp[ICN*CIN], wt[ICN*CIN];
  int t = threadIdx.x;
  for (int i = t; i < ICN*CIN; i += 256) { wg[i]=Wg[i]; wp[i]=Wp[i]; wt[i]=Wt[i]; }
  __syncthreads();
  int p = blockIdx.x*256 + t;
  float aG[ICN], aP[ICN], aT[ICN];
#pragma unroll
  for (int o=0;o<ICN;o++){ aG[o]=bg[o]; aP[o]=bp[o]; aT[o]=bt[o]; }
  for (int c=0;c<CIN;c++){
    float xv = x[c*HW + p];
#pragma unroll
    for (int o=0;o<ICN;o++){
      aG[o] = fmaf(wg[o*CIN+c], xv, aG[o]);
      aP[o] = fmaf(wp[o*CIN+c], xv, aP[o]);
      aT[o] = fmaf(wt[o*CIN+c], xv, aT[o]);
    }
  }
#pragma unroll
  for (int o=0;o<ICN;o++){ G[o*HW+p]=aG[o]; P[o*HW+p]=aP[o]; T[o*HW+p]=aT[o]; }
}

// ---------------- unfold Q (from G) and K (from P) as split bf16 ----------------
// Q/K: [4096][800] bf16, cols >= 784 zero. pads (1,2): y = iy*4 + dy - 1
__global__ __launch_bounds__(256) void unfold_qk(
    const float* __restrict__ G, const float* __restrict__ P,
    unsigned short* __restrict__ Qh, unsigned short* __restrict__ Ql,
    unsigned short* __restrict__ Kh, unsigned short* __restrict__ Kl){
  int row = blockIdx.x;
  int iy = row >> 6, ix = row & 63;
  for (int col = threadIdx.x; col < KDP; col += 256){
    float g = 0.f, p = 0.f;
    if (col < KD){
      int c = col / 49; int r = col - c*49; int dy = r / 7; int dx = r - dy*7;
      int y = (iy<<2) + dy - 1, x = (ix<<2) + dx - 1;
      if ((unsigned)y < HH && (unsigned)x < WID){
        int a = c*HW + (y<<8) + x;
        g = G[a]; p = P[a];
      }
    }
    size_t o = (size_t)row*KDP + col;
    unsigned short gh = f2bf(g); Qh[o]=gh; Ql[o]=f2bf(g - bf2f(gh));
    unsigned short ph = f2bf(p); Kh[o]=ph; Kl[o]=f2bf(p - bf2f(ph));
  }
}

// ---------------- unfold V transposed: Vt[col=0..895][row=0..4095] bf16 ----------------
__global__ __launch_bounds__(256) void unfold_vt(
    const float* __restrict__ T, unsigned short* __restrict__ Vt){
  int idx = blockIdx.x*256 + threadIdx.x;    // col*4096 + row
  int col = idx >> 12, row = idx & 4095;
  float t = 0.f;
  if (col < KD){
    int c = col / 49; int r = col - c*49; int dy = r / 7; int dx = r - dy*7;
    int iy = row >> 6, ix = row & 63;
    int y = (iy<<2) + dy - 1, x = (ix<<2) + dx - 1;
    if ((unsigned)y < HH && (unsigned)x < WID) t = T[c*HW + (y<<8) + x];
  }
  Vt[idx] = f2bf(t);
}

// ---------------- QK^T MFMA: ATT = 10 * (Qh+Ql)(Kh+Kl)^T, fp32 out ----------------
// 128x128 block tile, 4 waves (2x2) of 64x64. Split-bf16: 3 MFMA products.
__global__ __launch_bounds__(256) void gemm_qk_mfma(
    const unsigned short* __restrict__ Qh, const unsigned short* __restrict__ Ql,
    const unsigned short* __restrict__ Kh, const unsigned short* __restrict__ Kl,
    float* __restrict__ ATT){
  __shared__ alignas(16) short lds[4][128*32];   // Ah, Al, Bh, Bl tiles
  const int tid = threadIdx.x;
  const int lane = tid & 63, w = tid >> 6;
  const int wr = w >> 1, wc = w & 1;
  const int row0 = blockIdx.y*128, col0 = blockIdx.x*128;

  const unsigned short* base;
  { const unsigned short* s0[4] = {
      Qh + (size_t)row0*KDP, Ql + (size_t)row0*KDP,
      Kh + (size_t)col0*KDP, Kl + (size_t)col0*KDP };
    base = s0[w]; }

  // staging: wave w fills tile w. chunk j covers local rows 16j..16j+15.
  // lane s -> row r = 16j + (s>>2), slot s&3; source k-chunk = slot ^ ((r>>1)&3)
  const int r_lo = lane >> 2, slot = lane & 3;
  int goff[8];
#pragma unroll
  for (int j=0;j<8;j++){
    int r = j*16 + r_lo;
    int sw = slot ^ ((r>>1)&3);
    goff[j] = r*KDP + sw*8;
  }

  // fragment read offsets (shorts): row r at k-group g -> r*32 + (g^((r>>1)&3))*8
  const int lrow = lane & 15, g = lane >> 4;
  int offA[4], offB[4];
#pragma unroll
  for (int i=0;i<4;i++){
    int rA = wr*64 + i*16 + lrow;
    offA[i] = rA*32 + ((g ^ ((rA>>1)&3))<<3);
    int rB = wc*64 + i*16 + lrow;
    offB[i] = rB*32 + ((g ^ ((rB>>1)&3))<<3);
  }

  f32x4 acc[4][4] = {};

  for (int kb = 0; kb < KDP; kb += 32){
#pragma unroll
    for (int j=0;j<8;j++)
      __builtin_amdgcn_global_load_lds(
        (const __attribute__((address_space(1))) void*)(base + goff[j] + kb),
        (__attribute__((address_space(3))) void*)(&lds[w][j*512]), 16, 0, 0);
    __syncthreads();
    short8 ah[4], al[4], bh[4], bl[4];
#pragma unroll
    for (int i=0;i<4;i++){
      ah[i] = *(const short8*)&lds[0][offA[i]];
      al[i] = *(const short8*)&lds[1][offA[i]];
      bh[i] = *(const short8*)&lds[2][offB[i]];
      bl[i] = *(const short8*)&lds[3][offB[i]];
    }
#pragma unroll
    for (int i=0;i<4;i++)
#pragma unroll
      for (int j=0;j<4;j++){
        acc[i][j] = __builtin_amdgcn_mfma_f32_16x16x32_bf16(ah[i], bh[j], acc[i][j], 0,0,0);
        acc[i][j] = __builtin_amdgcn_mfma_f32_16x16x32_bf16(ah[i], bl[j], acc[i][j], 0,0,0);
        acc[i][j] = __builtin_amdgcn_mfma_f32_16x16x32_bf16(al[i], bh[j], acc[i][j], 0,0,0);
      }
    __syncthreads();
  }

  float* cbase = ATT + (size_t)(row0 + wr*64)*LL + col0 + wc*64;
#pragma unroll
  for (int i=0;i<4;i++)
#pragma unroll
    for (int j=0;j<4;j++)
#pragma unroll
      for (int r=0;r<4;r++)
        cbase[(size_t)(i*16 + g*4 + r)*LL + j*16 + lrow] = acc[i][j][r]*10.0f;
}

// ---------------- row softmax over 4096, fp32 in -> bf16 out ----------------
__global__ __launch_bounds__(256) void softmax_rows(
    const float* __restrict__ ATT, unsigned short* __restrict__ Pb){
  __shared__ float red[256];
  int t = threadIdx.x;
  const float* r = ATT + (size_t)blockIdx.x * LL;
  unsigned short* po = Pb + (size_t)blockIdx.x * LL;
  float v[16];
  float mx = -3.4e38f;
#pragma unroll
  for (int i=0;i<16;i++){ v[i] = r[t + (i<<8)]; mx = fmaxf(mx, v[i]); }
  red[t] = mx; __syncthreads();
  for (int s2=128;s2>0;s2>>=1){ if (t<s2) red[t]=fmaxf(red[t],red[t+s2]); __syncthreads(); }
  mx = red[0]; __syncthreads();
  float sum = 0.f;
#pragma unroll
  for (int i=0;i<16;i++){ v[i] = __expf(v[i]-mx); sum += v[i]; }
  red[t]=sum; __syncthreads();
  for (int s2=128;s2>0;s2>>=1){ if (t<s2) red[t]+=red[t+s2]; __syncthreads(); }
  float inv = 1.0f / red[0];
#pragma unroll
  for (int i=0;i<16;i++) po[t+(i<<8)] = f2bf(v[i]*inv);
}

// ---------------- PV MFMA: OUT[4096][800] = Pb[4096][4096] @ Vt^T ----------------
__global__ __launch_bounds__(256) void gemm_pv_mfma(
    const unsigned short* __restrict__ Pb, const unsigned short* __restrict__ Vt,
    float* __restrict__ OUT){
  __shared__ alignas(16) short ldsA[128*32];
  __shared__ alignas(16) short ldsB[128*32];
  const int tid = threadIdx.x;
  const int lane = tid & 63, w = tid >> 6;
  const int wr = w >> 1, wc = w & 1;
  const int row0 = blockIdx.y*128, col0 = blockIdx.x*128;

  const unsigned short* baseA = Pb + (size_t)row0*LL;
  const unsigned short* baseB = Vt + (size_t)col0*LL;
  const int r_lo = lane >> 2, slot = lane & 3;
  int goff0, goff1;
  { int r = w*16 + r_lo;       goff0 = r*LL + ((slot ^ ((r>>1)&3))<<3); }
  { int r = (4+w)*16 + r_lo;   goff1 = r*LL + ((slot ^ ((r>>1)&3))<<3); }

  const int lrow = lane & 15, g = lane >> 4;
  int offA[4], offB[4];
#pragma unroll
  for (int i=0;i<4;i++){
    int rA = wr*64 + i*16 + lrow;
    offA[i] = rA*32 + ((g ^ ((rA>>1)&3))<<3);
    int rB = wc*64 + i*16 + lrow;
    offB[i] = rB*32 + ((g ^ ((rB>>1)&3))<<3);
  }

  f32x4 acc[4][4] = {};

  for (int kb = 0; kb < LL; kb += 32){
    __builtin_amdgcn_global_load_lds(
      (const __attribute__((address_space(1))) void*)(baseA + goff0 + kb),
      (__attribute__((address_space(3))) void*)(&ldsA[w*512]), 16, 0, 0);
    __builtin_amdgcn_global_load_lds(
      (const __attribute__((address_space(1))) void*)(baseA + goff1 + kb),
      (__attribute__((address_space(3))) void*)(&ldsA[(4+w)*512]), 16, 0, 0);
    __builtin_amdgcn_global_load_lds(
      (const __attribute__((address_space(1))) void*)(baseB + goff0 + kb),
      (__attribute__((address_space(3))) void*)(&ldsB[w*512]), 16, 0, 0);
    __builtin_amdgcn_global_load_lds(
      (const __attribute__((address_space(1))) void*)(baseB + goff1 + kb),
      (__attribute__((address_space(3))) void*)(&ldsB[(4+w)*512]), 16, 0, 0);
    __syncthreads();
    short8 a[4], b[4];
#pragma unroll
    for (int i=0;i<4;i++){
      a[i] = *(const short8*)&ldsA[offA[i]];
      b[i] = *(const short8*)&ldsB[offB[i]];
    }
#pragma unroll
    for (int i=0;i<4;i++)
#pragma unroll
      for (int j=0;j<4;j++)
        acc[i][j] = __builtin_amdgcn_mfma_f32_16x16x32_bf16(a[i], b[j], acc[i][j], 0,0,0);
    __syncthreads();
  }

#pragma unroll
  for (int i=0;i<4;i++)
#pragma unroll
    for (int j=0;j<4;j++){
      int col = col0 + wc*64 + j*16 + lrow;
      if (col < KD){
#pragma unroll
        for (int r=0;r<4;r++)
          OUT[(size_t)(row0 + wr*64 + i*16 + g*4 + r)*KDP + col] = acc[i][j][r];
      }
    }
}

// ---------------- fold (pad=3) + divide by closed-form mask ----------------
__global__ __launch_bounds__(256) void fold_div(
    const float* __restrict__ OUT, float* __restrict__ ZI){
  int idx = blockIdx.x*256 + threadIdx.x;
  if (idx >= ICN*HW) return;
  int c = idx >> 16; int rem = idx & 65535; int y = rem >> 8; int x = rem & 255;
  int yc = y + 3, xc = x + 3;
  int i0 = (yc-3) >> 2; int i1 = yc >> 2; if (i1 > 63) i1 = 63;
  int j0 = (xc-3) >> 2; int j1 = xc >> 2; if (j1 > 63) j1 = 63;
  float s = 0.f;
  for (int i = i0; i <= i1; i++){
    int dy = yc - (i<<2);
    for (int j = j0; j <= j1; j++){
      int dx = xc - (j<<2);
      s += OUT[(size_t)((i<<6)+j)*KDP + c*49 + dy*7 + dx];
    }
  }
  float mask = (float)((i1-i0+1)*(j1-j0+1));
  ZI[idx] = s / mask;
}

// ---------------- out = x + conv1x1(zi, Ww, bw) ----------------
__global__ __launch_bounds__(256) void final_out(
    const float* __restrict__ xin, const float* __restrict__ ZI,
    const float* __restrict__ Ww, const float* __restrict__ bw,
    float* __restrict__ out){
  int idx = blockIdx.x*256 + threadIdx.x;   // co*HW + p
  int co = idx >> 16;
  int p = idx & 65535;
  float acc = xin[idx] + bw[co];
#pragma unroll
  for (int ic=0; ic<ICN; ic++)
    acc = fmaf(Ww[co*ICN+ic], ZI[ic*HW + p], acc);
  out[idx] = acc;
}

extern "C" void kernel_launch(void* const* d_in, const int* in_sizes, int n_in,
                              void* d_out, int out_size, void* d_ws, size_t ws_size,
                              hipStream_t stream) {
  const float* xb = (const float*)d_in[0];
  const float* Wg = (const float*)d_in[1];
  const float* bg = (const float*)d_in[2];
  const float* Wt = (const float*)d_in[3];
  const float* bt = (const float*)d_in[4];
  const float* Wp = (const float*)d_in[5];
  const float* bp = (const float*)d_in[6];
  const float* Ww = (const float*)d_in[7];
  const float* bw = (const float*)d_in[8];
  float* out = (float*)d_out;

  char* ws = (char*)d_ws;
  // byte offsets (total footprint ~113.2 MB; Pb/ZI/OUT alias dead regions)
  float*          G   = (float*)(ws + 0);
  float*          Pc  = (float*)(ws + 4194304);
  float*          T   = (float*)(ws + 8388608);
  unsigned short* Qh  = (unsigned short*)(ws + 12582912);
  unsigned short* Ql  = (unsigned short*)(ws + 19136512);
  unsigned short* Kh  = (unsigned short*)(ws + 25690112);
  unsigned short* Kl  = (unsigned short*)(ws + 32243712);
  unsigned short* Vt  = (unsigned short*)(ws + 38797312);
  float*          ATT = (float*)(ws + 46137344);
  unsigned short* Pb  = (unsigned short*)(ws + 0);         // alias G..Kl (dead)
  float*          ZI  = (float*)(ws + 33554432);           // alias Kl tail (dead)
  float*          OUTm= (float*)(ws + 46137344);           // alias ATT (dead)

  for (int b = 0; b < NB; b++){
    const float* x = xb + (size_t)b*CIN*HW;
    conv1x1_3<<<HW/256, 256, 0, stream>>>(x, Wg,bg, Wp,bp, Wt,bt, G,Pc,T);
    unfold_qk<<<LL, 256, 0, stream>>>(G, Pc, Qh, Ql, Kh, Kl);
    unfold_vt<<<NVT*LL/256, 256, 0, stream>>>(T, Vt);
    gemm_qk_mfma<<<dim3(LL/128, LL/128), 256, 0, stream>>>(Qh, Ql, Kh, Kl, ATT);
    softmax_rows<<<LL, 256, 0, stream>>>(ATT, Pb);
    gemm_pv_mfma<<<dim3(NVT/128, LL/128), 256, 0, stream>>>(Pb, Vt, OUTm);
    fold_div<<<(ICN*HW)/256, 256, 0, stream>>>(OUTm, ZI);
    final_out<<<CIN*HW/256, 256, 0, stream>>>(x, ZI, Ww, bw, out + (size_t)b*CIN*HW);
  }
}

// Round 4
// 1189.250 us; speedup vs baseline: 3.1105x; 1.0381x over previous
//
#include <hip/hip_runtime.h>

#define CIN 64
#define ICN 16
#define HH 256
#define WID 256
#define HW (HH*WID)
#define LL 4096          // 64*64 patches
#define KD 784           // 16*49
#define KDP 800          // PV output row stride
#define KQ 832           // i8 QK row stride (784 padded to 64 multiple)
#define NVT 896          // V^T rows (784 padded to 128 multiple)
#define NB 4

typedef __attribute__((ext_vector_type(8))) short short8;
typedef __attribute__((ext_vector_type(4))) float f32x4;
typedef __attribute__((ext_vector_type(4))) int i32x4;

__device__ __forceinline__ unsigned short f2bf(float x){
  union { float f; unsigned u; } v; v.f = x;
  unsigned r = v.u + 0x7FFF + ((v.u >> 16) & 1);
  return (unsigned short)(r >> 16);
}

// ---------------- conv1x1 (64 -> 16) for G, P, T at once ----------------
__global__ __launch_bounds__(256) void conv1x1_3(
    const float* __restrict__ x,
    const float* __restrict__ Wg, const float* __restrict__ bg,
    const float* __restrict__ Wp, const float* __restrict__ bp,
    const float* __restrict__ Wt, const float* __restrict__ bt,
    float* __restrict__ G, float* __restrict__ P, float* __restrict__ T) {
  __shared__ float wg[ICN*CIN], wp[ICN*CIN], wt[ICN*CIN];
  int t = threadIdx.x;
  for (int i = t; i < ICN*CIN; i += 256) { wg[i]=Wg[i]; wp[i]=Wp[i]; wt[i]=Wt[i]; }
  __syncthreads();
  int p = blockIdx.x*256 + t;
  float aG[ICN], aP[ICN], aT[ICN];
#pragma unroll
  for (int o=0;o<ICN;o++){ aG[o]=bg[o]; aP[o]=bp[o]; aT[o]=bt[o]; }
  for (int c=0;c<CIN;c++){
    float xv = x[c*HW + p];
#pragma unroll
    for (int o=0;o<ICN;o++){
      aG[o] = fmaf(wg[o*CIN+c], xv, aG[o]);
      aP[o] = fmaf(wp[o*CIN+c], xv, aP[o]);
      aT[o] = fmaf(wt[o*CIN+c], xv, aT[o]);
    }
  }
#pragma unroll
  for (int o=0;o<ICN;o++){ G[o*HW+p]=aG[o]; P[o*HW+p]=aP[o]; T[o*HW+p]=aT[o]; }
}

// ---------------- unfold Q (from G) and K (from P), 2-plane i8 quantized ----------------
// block = one patch row. rs = rowmax/127; q ~= rs*(a0 + a1/256).
__global__ __launch_bounds__(256) void unfold_qk_q(
    const float* __restrict__ G, const float* __restrict__ P,
    char* __restrict__ Q0, char* __restrict__ Q1,
    char* __restrict__ K0, char* __restrict__ K1,
    float* __restrict__ sQ, float* __restrict__ sK){
  __shared__ float gb[KQ], pb[KQ];
  __shared__ float redg[256], redp[256];
  int row = blockIdx.x;
  int iy = row >> 6, ix = row & 63;
  int t = threadIdx.x;
  float gmax = 0.f, pmax = 0.f;
  for (int col = t; col < KQ; col += 256){
    float g = 0.f, p = 0.f;
    if (col < KD){
      int c = col / 49; int r = col - c*49; int dy = r / 7; int dx = r - dy*7;
      int y = (iy<<2) + dy - 1, x = (ix<<2) + dx - 1;
      if ((unsigned)y < HH && (unsigned)x < WID){
        int a = c*HW + (y<<8) + x;
        g = G[a]; p = P[a];
      }
    }
    gb[col] = g; pb[col] = p;
    gmax = fmaxf(gmax, fabsf(g)); pmax = fmaxf(pmax, fabsf(p));
  }
  redg[t]=gmax; redp[t]=pmax; __syncthreads();
  for (int s2=128;s2>0;s2>>=1){
    if (t<s2){ redg[t]=fmaxf(redg[t],redg[t+s2]); redp[t]=fmaxf(redp[t],redp[t+s2]); }
    __syncthreads();
  }
  float mg = redg[0], mp = redp[0];
  float rsg = mg > 0.f ? mg*(1.f/127.f) : 1.f;
  float rsp = mp > 0.f ? mp*(1.f/127.f) : 1.f;
  if (t==0){ sQ[row]=rsg; sK[row]=rsp; }
  float ig = 1.f/rsg, ip = 1.f/rsp;
  if (t < KQ/4){
    char q0[4],q1[4],k0[4],k1[4];
#pragma unroll
    for (int u=0;u<4;u++){
      float xg = gb[t*4+u]*ig;
      float a0 = rintf(xg);
      int ia1 = (int)rintf((xg - a0)*256.f);
      ia1 = ia1>127?127:(ia1<-127?-127:ia1);
      q0[u] = (char)(int)a0; q1[u] = (char)ia1;
      float xp = pb[t*4+u]*ip;
      float b0 = rintf(xp);
      int ib1 = (int)rintf((xp - b0)*256.f);
      ib1 = ib1>127?127:(ib1<-127?-127:ib1);
      k0[u] = (char)(int)b0; k1[u] = (char)ib1;
    }
    size_t o = (size_t)row*KQ + t*4;
    *(char4*)(Q0+o) = make_char4(q0[0],q0[1],q0[2],q0[3]);
    *(char4*)(Q1+o) = make_char4(q1[0],q1[1],q1[2],q1[3]);
    *(char4*)(K0+o) = make_char4(k0[0],k0[1],k0[2],k0[3]);
    *(char4*)(K1+o) = make_char4(k1[0],k1[1],k1[2],k1[3]);
  }
}

// ---------------- unfold V transposed: Vt[col=0..895][row=0..4095] bf16 ----------------
__global__ __launch_bounds__(256) void unfold_vt(
    const float* __restrict__ T, unsigned short* __restrict__ Vt){
  int idx = blockIdx.x*256 + threadIdx.x;    // col*4096 + row
  int col = idx >> 12, row = idx & 4095;
  float t = 0.f;
  if (col < KD){
    int c = col / 49; int r = col - c*49; int dy = r / 7; int dx = r - dy*7;
    int iy = row >> 6, ix = row & 63;
    int y = (iy<<2) + dy - 1, x = (ix<<2) + dx - 1;
    if ((unsigned)y < HH && (unsigned)x < WID) t = T[c*HW + (y<<8) + x];
  }
  Vt[idx] = f2bf(t);
}

// ---------------- QK^T i8 MFMA: logits = 10*rs_i*cs_j*(accH + accC/256) ----------------
// 128x128 tile, 4 waves (2x2) of 64x64, BK=64, mfma_i32_16x16x64_i8.
__global__ __launch_bounds__(256) void gemm_qk_i8(
    const char* __restrict__ Q0, const char* __restrict__ Q1,
    const char* __restrict__ K0, const char* __restrict__ K1,
    const float* __restrict__ sQ, const float* __restrict__ sK,
    float* __restrict__ ATT){
  __shared__ alignas(16) char lds[4][128*64];   // Q0,Q1,K0,K1 tiles (32 KB)
  const int tid = threadIdx.x;
  const int lane = tid & 63, w = tid >> 6;
  const int wr = w >> 1, wc = w & 1;
  const int row0 = blockIdx.y*128, col0 = blockIdx.x*128;

  const char* base;
  { const char* s0[4] = {
      Q0 + (size_t)row0*KQ, Q1 + (size_t)row0*KQ,
      K0 + (size_t)col0*KQ, K1 + (size_t)col0*KQ };
    base = s0[w]; }

  // staging: wave w fills tile w, 8 loads of 16 rows. lane -> row r=16j+(lane>>2),
  // 16B slot = lane&3, source slot pre-swizzled = slot ^ ((r>>1)&3).
  const int r_lo = lane >> 2, slot = lane & 3;
  int goff[8];
#pragma unroll
  for (int j=0;j<8;j++){
    int r = j*16 + r_lo;
    goff[j] = r*KQ + ((slot ^ ((r>>1)&3))<<4);
  }

  // fragment reads (bytes): row r, k-group g=lane>>4 -> r*64 + (g^((r>>1)&3))*16
  const int lrow = lane & 15, g = lane >> 4;
  int offA[4], offB[4];
#pragma unroll
  for (int i=0;i<4;i++){
    int rA = wr*64 + i*16 + lrow;
    offA[i] = rA*64 + ((g ^ ((rA>>1)&3))<<4);
    int rB = wc*64 + i*16 + lrow;
    offB[i] = rB*64 + ((g ^ ((rB>>1)&3))<<4);
  }

  i32x4 accH[4][4] = {};
  i32x4 accC[4][4] = {};

  for (int kb = 0; kb < KQ; kb += 64){
#pragma unroll
    for (int j=0;j<8;j++)
      __builtin_amdgcn_global_load_lds(
        (const __attribute__((address_space(1))) void*)(base + goff[j] + kb),
        (__attribute__((address_space(3))) void*)(&lds[w][j*1024]), 16, 0, 0);
    __syncthreads();
    i32x4 a0[4], a1[4], b0[4], b1[4];
#pragma unroll
    for (int i=0;i<4;i++){
      a0[i] = *(const i32x4*)&lds[0][offA[i]];
      a1[i] = *(const i32x4*)&lds[1][offA[i]];
      b0[i] = *(const i32x4*)&lds[2][offB[i]];
      b1[i] = *(const i32x4*)&lds[3][offB[i]];
    }
#pragma unroll
    for (int i=0;i<4;i++)
#pragma unroll
      for (int j=0;j<4;j++){
        accH[i][j] = __builtin_amdgcn_mfma_i32_16x16x64_i8(a0[i], b0[j], accH[i][j], 0,0,0);
        accC[i][j] = __builtin_amdgcn_mfma_i32_16x16x64_i8(a0[i], b1[j], accC[i][j], 0,0,0);
        accC[i][j] = __builtin_amdgcn_mfma_i32_16x16x64_i8(a1[i], b0[j], accC[i][j], 0,0,0);
      }
    __syncthreads();
  }

#pragma unroll
  for (int j=0;j<4;j++){
    int col = col0 + wc*64 + j*16 + lrow;
    float cs = sK[col]*10.f;
#pragma unroll
    for (int i=0;i<4;i++){
#pragma unroll
      for (int r=0;r<4;r++){
        int row = row0 + wr*64 + i*16 + g*4 + r;
        float rs = sQ[row];
        ATT[(size_t)row*LL + col] =
          rs*cs*((float)accH[i][j][r] + (float)accC[i][j][r]*0.00390625f);
      }
    }
  }
}

// ---------------- row softmax over 4096, fp32 in -> bf16 out ----------------
__global__ __launch_bounds__(256) void softmax_rows(
    const float* __restrict__ ATT, unsigned short* __restrict__ Pb){
  __shared__ float red[256];
  int t = threadIdx.x;
  const float* r = ATT + (size_t)blockIdx.x * LL;
  unsigned short* po = Pb + (size_t)blockIdx.x * LL;
  float v[16];
  float mx = -3.4e38f;
#pragma unroll
  for (int i=0;i<16;i++){ v[i] = r[t + (i<<8)]; mx = fmaxf(mx, v[i]); }
  red[t] = mx; __syncthreads();
  for (int s2=128;s2>0;s2>>=1){ if (t<s2) red[t]=fmaxf(red[t],red[t+s2]); __syncthreads(); }
  mx = red[0]; __syncthreads();
  float sum = 0.f;
#pragma unroll
  for (int i=0;i<16;i++){ v[i] = __expf(v[i]-mx); sum += v[i]; }
  red[t]=sum; __syncthreads();
  for (int s2=128;s2>0;s2>>=1){ if (t<s2) red[t]+=red[t+s2]; __syncthreads(); }
  float inv = 1.0f / red[0];
#pragma unroll
  for (int i=0;i<16;i++) po[t+(i<<8)] = f2bf(v[i]*inv);
}

// ---------------- PV MFMA: OUT[4096][800] = Pb[4096][4096] @ Vt^T ----------------
__global__ __launch_bounds__(256) void gemm_pv_mfma(
    const unsigned short* __restrict__ Pb, const unsigned short* __restrict__ Vt,
    float* __restrict__ OUT){
  __shared__ alignas(16) short ldsA[128*32];
  __shared__ alignas(16) short ldsB[128*32];
  const int tid = threadIdx.x;
  const int lane = tid & 63, w = tid >> 6;
  const int wr = w >> 1, wc = w & 1;
  const int row0 = blockIdx.y*128, col0 = blockIdx.x*128;

  const unsigned short* baseA = Pb + (size_t)row0*LL;
  const unsigned short* baseB = Vt + (size_t)col0*LL;
  const int r_lo = lane >> 2, slot = lane & 3;
  int goff0, goff1;
  { int r = w*16 + r_lo;       goff0 = r*LL + ((slot ^ ((r>>1)&3))<<3); }
  { int r = (4+w)*16 + r_lo;   goff1 = r*LL + ((slot ^ ((r>>1)&3))<<3); }

  const int lrow = lane & 15, g = lane >> 4;
  int offA[4], offB[4];
#pragma unroll
  for (int i=0;i<4;i++){
    int rA = wr*64 + i*16 + lrow;
    offA[i] = rA*32 + ((g ^ ((rA>>1)&3))<<3);
    int rB = wc*64 + i*16 + lrow;
    offB[i] = rB*32 + ((g ^ ((rB>>1)&3))<<3);
  }

  f32x4 acc[4][4] = {};

  for (int kb = 0; kb < LL; kb += 32){
    __builtin_amdgcn_global_load_lds(
      (const __attribute__((address_space(1))) void*)(baseA + goff0 + kb),
      (__attribute__((address_space(3))) void*)(&ldsA[w*512]), 16, 0, 0);
    __builtin_amdgcn_global_load_lds(
      (const __attribute__((address_space(1))) void*)(baseA + goff1 + kb),
      (__attribute__((address_space(3))) void*)(&ldsA[(4+w)*512]), 16, 0, 0);
    __builtin_amdgcn_global_load_lds(
      (const __attribute__((address_space(1))) void*)(baseB + goff0 + kb),
      (__attribute__((address_space(3))) void*)(&ldsB[w*512]), 16, 0, 0);
    __builtin_amdgcn_global_load_lds(
      (const __attribute__((address_space(1))) void*)(baseB + goff1 + kb),
      (__attribute__((address_space(3))) void*)(&ldsB[(4+w)*512]), 16, 0, 0);
    __syncthreads();
    short8 a[4], b[4];
#pragma unroll
    for (int i=0;i<4;i++){
      a[i] = *(const short8*)&ldsA[offA[i]];
      b[i] = *(const short8*)&ldsB[offB[i]];
    }
#pragma unroll
    for (int i=0;i<4;i++)
#pragma unroll
      for (int j=0;j<4;j++)
        acc[i][j] = __builtin_amdgcn_mfma_f32_16x16x32_bf16(a[i], b[j], acc[i][j], 0,0,0);
    __syncthreads();
  }

#pragma unroll
  for (int i=0;i<4;i++)
#pragma unroll
    for (int j=0;j<4;j++){
      int col = col0 + wc*64 + j*16 + lrow;
      if (col < KD){
#pragma unroll
        for (int r=0;r<4;r++)
          OUT[(size_t)(row0 + wr*64 + i*16 + g*4 + r)*KDP + col] = acc[i][j][r];
      }
    }
}

// ---------------- fused fold (pad=3) + mask-divide + conv1x1 + residual ----------------
__global__ __launch_bounds__(256) void fold_final(
    const float* __restrict__ OUT, const float* __restrict__ xin,
    const float* __restrict__ Ww, const float* __restrict__ bw,
    float* __restrict__ out){
  __shared__ float wsh[CIN*ICN];
  __shared__ float bsh[CIN];
  int t = threadIdx.x;
  for (int i=t;i<CIN*ICN;i+=256) wsh[i]=Ww[i];
  if (t<CIN) bsh[t]=bw[t];
  __syncthreads();
  int p = blockIdx.x*256 + t;         // pixel
  int y = p >> 8, x = p & 255;
  int yc = y + 3, xc = x + 3;
  int i0 = (yc-3) >> 2; int i1 = yc >> 2; if (i1 > 63) i1 = 63;
  int j0 = (xc-3) >> 2; int j1 = xc >> 2; if (j1 > 63) j1 = 63;
  float zi[ICN] = {};
  for (int i = i0; i <= i1; i++){
    int dy = yc - (i<<2);
    for (int j = j0; j <= j1; j++){
      int dx = xc - (j<<2);
      const float* bp = &OUT[(size_t)((i<<6)+j)*KDP + dy*7 + dx];
#pragma unroll
      for (int c=0;c<ICN;c++) zi[c] += bp[c*49];
    }
  }
  float inv = 1.0f / (float)((i1-i0+1)*(j1-j0+1));
#pragma unroll
  for (int c=0;c<ICN;c++) zi[c] *= inv;
#pragma unroll
  for (int co=0;co<CIN;co++){
    float acc = xin[co*HW + p] + bsh[co];
    const float4* w4 = (const float4*)&wsh[co*ICN];
#pragma unroll
    for (int c4=0;c4<4;c4++){
      float4 wv = w4[c4];
      acc = fmaf(wv.x, zi[c4*4+0], acc);
      acc = fmaf(wv.y, zi[c4*4+1], acc);
      acc = fmaf(wv.z, zi[c4*4+2], acc);
      acc = fmaf(wv.w, zi[c4*4+3], acc);
    }
    out[co*HW + p] = acc;
  }
}

extern "C" void kernel_launch(void* const* d_in, const int* in_sizes, int n_in,
                              void* d_out, int out_size, void* d_ws, size_t ws_size,
                              hipStream_t stream) {
  const float* xb = (const float*)d_in[0];
  const float* Wg = (const float*)d_in[1];
  const float* bg = (const float*)d_in[2];
  const float* Wt = (const float*)d_in[3];
  const float* bt = (const float*)d_in[4];
  const float* Wp = (const float*)d_in[5];
  const float* bp = (const float*)d_in[6];
  const float* Ww = (const float*)d_in[7];
  const float* bw = (const float*)d_in[8];
  float* out = (float*)d_out;

  char* ws = (char*)d_ws;
  // byte offsets, total ~103 MB (Pb/OUT alias dead regions)
  float*          G   = (float*)(ws + 0);
  float*          Pc  = (float*)(ws + 4194304);
  float*          T   = (float*)(ws + 8388608);
  char*           Q0  = (char*)(ws + 12582912);   // 4096*832 i8
  char*           Q1  = (char*)(ws + 15990784);
  char*           K0  = (char*)(ws + 19398656);
  char*           K1  = (char*)(ws + 22806528);
  float*          sQ  = (float*)(ws + 26214400);
  float*          sK  = (float*)(ws + 26230784);
  float*          ATT = (float*)(ws + 33554432);  // 64 MB
  unsigned short* Vt  = (unsigned short*)(ws + 100663296);  // 7.34 MB
  unsigned short* Pb  = (unsigned short*)(ws + 0);          // alias (dead at softmax)
  float*          OUTm= (float*)(ws + 33554432);            // alias ATT (dead)

  for (int b = 0; b < NB; b++){
    const float* x = xb + (size_t)b*CIN*HW;
    conv1x1_3<<<HW/256, 256, 0, stream>>>(x, Wg,bg, Wp,bp, Wt,bt, G,Pc,T);
    unfold_qk_q<<<LL, 256, 0, stream>>>(G, Pc, Q0, Q1, K0, K1, sQ, sK);
    unfold_vt<<<NVT*LL/256, 256, 0, stream>>>(T, Vt);
    gemm_qk_i8<<<dim3(LL/128, LL/128), 256, 0, stream>>>(Q0, Q1, K0, K1, sQ, sK, ATT);
    softmax_rows<<<LL, 256, 0, stream>>>(ATT, Pb);
    gemm_pv_mfma<<<dim3(NVT/128, LL/128), 256, 0, stream>>>(Pb, Vt, OUTm);
    fold_final<<<HW/256, 256, 0, stream>>>(OUTm, x, Ww, bw, out + (size_t)b*CIN*HW);
  }
}